// Round 8
// baseline (361.342 us; speedup 1.0000x reference)
//
#include <hip/hip_runtime.h>
#include <cstdint>

#define D 128
#define T 64
#define B 512
#define EPSF 1e-5f

// wave-uniform lane broadcast via v_readlane (no LDS/ds_bpermute)
__device__ __forceinline__ float lane_bcast(float x, int l) {
    return __int_as_float(__builtin_amdgcn_readlane(__float_as_int(x), l));
}

// ---------------------------------------------------------------------------
// prep: vT[k*D+i] = v[i][k] = W[i][k]/max(norm_i,1e-12); vd[i]=v[i][i]; absb=|b|
// ---------------------------------------------------------------------------
__global__ __launch_bounds__(64) void prep_kernel(const float* __restrict__ W,
                                                  const float* __restrict__ b,
                                                  float* __restrict__ vT,
                                                  float* __restrict__ vd,
                                                  float* __restrict__ absb) {
    const int i = blockIdx.x;
    const int l = threadIdx.x;
    float w0 = W[i * D + l];
    float w1 = W[i * D + l + 64];
    float p = w0 * w0 + w1 * w1;
#pragma unroll
    for (int off = 32; off; off >>= 1) p += __shfl_xor(p, off);
    float norm = sqrtf(p);
    float scale = norm > 1e-12f ? norm : 1e-12f;
    float v0 = w0 / scale;
    float v1 = w1 / scale;
    vT[l * D + i] = v0;
    vT[(l + 64) * D + i] = v1;
    if (i < 64) {
        if (l == i) vd[i] = v0;
    } else {
        if (l == i - 64) vd[i] = v1;
    }
    if (i == 0) {
        absb[l] = fabsf(b[l]);
        absb[l + 64] = fabsf(b[l + 64]);
    }
}

// ---------------------------------------------------------------------------
// main RNN kernel. One wave per batch column; lane owns rows (lane, lane+64).
// NO barriers in the t-loop (round-1: per-step vmcnt(0) drains cost −62%).
// Matvec reads v from AGPR-pinned registers (round-4).
//
// Round-7 lesson: judge work & bank conflicts are NOT on the critical path
// (−100K conflict-cycles, flat timing). Remaining stall theory: the SERIAL
// cross-lane loops (probe, Gauss-Seidel sweep) where each iteration carries
// ballot -> ffs -> readlane -> ds_read(~120cy) -> fma -> re-ballot with
// 1 wave/SIMD. Round-8 changes (all bit-equivalent):
//  (a) probe path removed: the parallel judge subsumes it exactly (delta=0
//      candidates of non-violators reproduce the q0 candidate); q0 shortcut
//      kept, guarded against the all-violate corner where no delta-0
//      candidate exists.
//  (b) vpair float2 layout: sweep column read = ONE ds_read_b64.
//  (c) speculative sweep: prefetch first violator's column at correction
//      entry (latency hidden under sstage/deltas/judge); in-loop, issue the
//      predicted-next column read at iteration top so the ~120cy latency
//      hides under the update+re-ballot ALU. Misprediction -> fresh read.
//
// LDS (132.6 KB, 1 block/CU):
//   vsh  [k*128 + (i ^ ((k&7)<<2))] = v[i][k]      judge b128 column scans
//   vpair[(k<<6) + (i ^ ((k&3)<<2))] = {v[i][k],
//                                       v[i+64][k]} sweep b64 pair reads
//   aeps_arr/sstage: uniform-address judge broadcasts
// ---------------------------------------------------------------------------
__global__ __launch_bounds__(128, 1) void rnn_kernel(const float* __restrict__ input,
                                                     const float* __restrict__ target,
                                                     const float* __restrict__ returns,
                                                     const float* __restrict__ vTg,
                                                     const float* __restrict__ vdg,
                                                     const float* __restrict__ absbg,
                                                     float* __restrict__ out) {
    __shared__ float vsh[D * D];                    // 64 KB
    __shared__ __align__(16) float2 vpair[D * 64];  // 64 KB
    __shared__ __align__(16) float aeps_arr[D];     // judge broadcast (const)
    __shared__ __align__(16) float sstage[2][D];    // judge broadcast (per wave)

    const int tid = threadIdx.x;
    // cooperative swizzled load of vT (plain layout in ws -> swizzled LDS)
    {
        const float4* src = (const float4*)vTg;
        float4* dst = (float4*)vsh;
#pragma unroll
        for (int c = 0; c < 32; ++c) {
            int f = c * 128 + tid;          // source float4 index
            int k = f >> 5;                 // row k of vT
            int i = (f & 31) << 2;          // starting i of this float4
            int ck = (k & 7) << 2;
            int d4 = k * 32 + (((i ^ ck)) >> 2);
            dst[d4] = src[f];
        }
    }
    // vpair build (verified in round-1): element (i,k) at (k<<6)+(i^((k&3)<<2))
#pragma unroll
    for (int c = 0; c < 32; ++c) {
        int f = c * 128 + tid;              // float4 index (0..4095)
        int k = f >> 5;                     // column of v
        int i0 = (f & 31) << 1;             // even logical pair index
        float4 val;
        val.x = vTg[k * D + i0];
        val.y = vTg[k * D + i0 + 64];
        val.z = vTg[k * D + i0 + 1];
        val.w = vTg[k * D + i0 + 65];
        *(float4*)&vpair[(k << 6) + (i0 ^ ((k & 3) << 2))] = val;
    }
    aeps_arr[tid] = absbg[tid] + EPSF;      // tid covers 0..127 = D
    __syncthreads();

    const int w = tid >> 6;
    const int lane = tid & 63;
    const int b = blockIdx.x * 2 + w;
    const int rlo = lane, rhi = lane + 64;

    const float tgt_lo = target[rlo], tgt_hi = target[rhi];
    const float a_lo = absbg[rlo], a_hi = absbg[rhi];
    const float aeps_lo = a_lo + EPSF, aeps_hi = a_hi + EPSF;
    const float vd_lo = vdg[rlo], vd_hi = vdg[rhi];
    const float rvd_lo = 1.0f / vd_lo, rvd_hi = 1.0f / vd_hi;

    // row-read xor bases: vsh[k*128 + ax[k&7]] (+64 for hi row)
    int ax[8];
#pragma unroll
    for (int c = 0; c < 8; ++c) ax[c] = rlo ^ (c << 2);

    // ---- register-resident v rows, PINNED in AGPRs (one-time LDS read;
    //      "+a" asm result is non-rematerializable -> stays resident) ----
    float vl[D], vh[D];
#pragma unroll
    for (int k = 0; k < D; ++k) {
        int base = k * 128 + ax[k & 7];
        vl[k] = vsh[base];
        vh[k] = vsh[base + 64];
        asm volatile("" : "+a"(vl[k]), "+a"(vh[k]));
    }

    // parallel-judge column bases: candidate j=lane reads float4 at
    // Abase[c] + 32*a  (logical i0 = a*32 + c*4); candidate lane+64 at +8192
    const int cj = (lane & 7) << 2;
    int Abase[8];
#pragma unroll
    for (int c = 0; c < 8; ++c) Abase[c] = lane * 128 + ((c << 2) ^ cj);

    // sweep pair-read swizzled lane offset helper is computed per-j inline

    float h_lo = input[rlo * T * B + b];
    float h_hi = input[rhi * T * B + b];
    out[rlo * T * B + b] = h_lo;
    out[rhi * T * B + b] = h_hi;

    float r_lo = returns[rlo * T * B + b];
    float r_hi = returns[rhi * T * B + b];

    for (int t = 1; t < T; ++t) {
        // ---- adj = h*(1+r)/(1 + sum(h*r)) ----
        float num_lo = h_lo * (1.0f + r_lo);
        float num_hi = h_hi * (1.0f + r_hi);
        float p = h_lo * r_lo + h_hi * r_hi;
#pragma unroll
        for (int off = 32; off; off >>= 1) p += __shfl_xor(p, off);
        float den = 1.0f + p;
        float adj_lo = num_lo / den;
        float adj_hi = num_hi / den;

        if (t < T - 1) {
            r_lo = returns[rlo * T * B + t * B + b];
            r_hi = returns[rhi * T * B + t * B + b];
        }

        const float x_lo = adj_lo - tgt_lo;
        const float x_hi = adj_hi - tgt_hi;

        // ---- s = v @ (adj - pi_bar): readlane broadcast + AGPR-resident v.
        //      k ascending, single accumulator per row -> bit-identical to
        //      round-0. Zero LDS traffic. ----
        float s_lo = 0.0f, s_hi = 0.0f;
#pragma unroll
        for (int k = 0; k < 64; ++k) {
            float xb = lane_bcast(x_lo, k);
            s_lo = fmaf(vl[k], xb, s_lo);
            s_hi = fmaf(vh[k], xb, s_hi);
        }
#pragma unroll
        for (int k = 0; k < 64; ++k) {
            float xb = lane_bcast(x_hi, k);
            s_lo = fmaf(vl[64 + k], xb, s_lo);
            s_hi = fmaf(vh[64 + k], xb, s_hi);
        }

        h_lo = adj_lo;
        h_hi = adj_hi;

        // ================= correction ======================================
        bool viol_lo = (s_lo > a_lo) || (s_lo < -a_lo);
        bool viol_hi = (s_hi > a_hi) || (s_hi < -a_hi);
        uint64_t mlo = __ballot(viol_lo);
        uint64_t mhi = __ballot(viol_hi);

        if ((mlo | mhi) != 0ull) {
            // ---- prefetch the first violator's column pair NOW: it is the
            //      sweep's first target regardless of what judge decides.
            //      ~600cy of judge/delta work hides the read latency. ----
            int j0 = mlo ? (int)__ffsll((unsigned long long)mlo) - 1
                         : 64 + (int)__ffsll((unsigned long long)mhi) - 1;
            float2 p0 = vpair[(j0 << 6) + (lane ^ ((j0 & 3) << 2))];

            // stage s for uniform-broadcast reads in the judge (wave-private)
            sstage[w][rlo] = s_lo;
            sstage[w][rhi] = s_hi;

            // per-lane deltas (reference lam formulas, IEEE div)
            float dl = 0.0f, dh = 0.0f;
            if (s_lo > a_lo) dl = (a_lo - s_lo) / vd_lo;
            else if (s_lo < -a_lo) dl = (-a_lo - s_lo) / vd_lo;
            if (s_hi > a_hi) dh = (a_hi - s_hi) / vd_hi;
            else if (s_hi < -a_hi) dh = (-a_hi - s_hi) / vd_hi;

            bool judge;

            // q0 shortcut: all strictly inside a+eps. Valid whenever a
            // zero-delta candidate exists (i.e. not ALL rows violate) —
            // then some candidate reproduces s exactly, so judge is true.
            bool allviol = (mlo == ~0ull) && (mhi == ~0ull);
            bool in_lo = (s_lo < aeps_lo) && (s_lo > -aeps_lo);
            bool in_hi = (s_hi < aeps_hi) && (s_hi > -aeps_hi);
            judge = !allviol && (__ballot(in_lo && in_hi) == ~0ull);

            if (!judge) {
                // ---- parallel judge: lane tests candidates j=lane, lane+64.
                // Subsumes the old V<=8 serial probe exactly: non-violator
                // candidates have dl/dh = 0 and reproduce the q0 candidate;
                // violator candidates match the probe's trials. s/aeps via
                // uniform-address b128 reads (HW broadcast); early-exit when
                // every candidate already failed (max only grows -> exact).
                float m1 = -1.0f, m2 = -1.0f;   // only the sign of max matters
                bool dead = false;
#pragma unroll
                for (int a = 0; a < 4; ++a) {
                    if (!dead) {
#pragma unroll
                        for (int c = 0; c < 8; ++c) {
                            const int i0 = a * 32 + c * 4;
                            const float* p1 = &vsh[Abase[c] + 32 * a];
                            float4 c1 = *(const float4*)p1;
                            float4 c2 = *(const float4*)(p1 + 8192);
                            float4 s4 = *(const float4*)&sstage[w][i0];   // uniform
                            float4 ae4 = *(const float4*)&aeps_arr[i0];   // uniform
#pragma unroll
                            for (int e = 0; e < 4; ++e) {
                                float sv = ((const float*)&s4)[e];
                                float ae = ((const float*)&ae4)[e];
                                float f1 = ((const float*)&c1)[e];
                                float f2 = ((const float*)&c2)[e];
                                m1 = fmaxf(m1, fabsf(fmaf(f1, dl, sv)) - ae);
                                m2 = fmaxf(m2, fabsf(fmaf(f2, dh, sv)) - ae);
                            }
                        }
                        if (a < 3) {
                            if ((__ballot(m1 < 0.0f) | __ballot(m2 < 0.0f)) == 0ull)
                                dead = true;   // all candidates failed already
                        }
                    }
                }
                judge = ((__ballot(m1 < 0.0f) | __ballot(m2 < 0.0f)) != 0ull);
            }

            if (judge) {
                // ---- Gauss-Seidel sweep (ascending j, violators only),
                //      speculative column prefetch version. Visit order,
                //      delta arithmetic, and update order identical to the
                //      original loop; column values identical (vpair holds
                //      the same v entries). ----
                uint64_t rem_lo = ~0ull, rem_hi = ~0ull;
                uint64_t m1b = mlo, m2b = mhi;   // = ballot of current s & rem
                int jcur = j0;
                float2 pcur = p0;
                while (jcur >= 0) {
                    // speculate next target: next set bit after jcur in the
                    // CURRENT masks (usually unchanged by the update below);
                    // issue its read now so latency hides under the ALU.
                    uint64_t t1 = m1b, t2 = m2b;
                    if (jcur < 64) {
                        t1 &= (jcur == 63) ? 0ull : (~0ull << (jcur + 1));
                    } else {
                        t1 = 0ull;
                        t2 &= (jcur == 127) ? 0ull : (~0ull << (jcur - 63));
                    }
                    int jspec = t1 ? (int)__ffsll((unsigned long long)t1) - 1
                              : (t2 ? 64 + (int)__ffsll((unsigned long long)t2) - 1 : -1);
                    float2 pspec;
                    pspec.x = 0.0f; pspec.y = 0.0f;
                    if (jspec >= 0)
                        pspec = vpair[(jspec << 6) + (lane ^ ((jspec & 3) << 2))];

                    // apply delta at jcur (same formulas as original sweep)
                    float dl2 = (s_lo > a_lo) ? (a_lo - s_lo) * rvd_lo
                               : ((s_lo < -a_lo) ? (-a_lo - s_lo) * rvd_lo : 0.0f);
                    float dh2 = (s_hi > a_hi) ? (a_hi - s_hi) * rvd_hi
                               : ((s_hi < -a_hi) ? (-a_hi - s_hi) * rvd_hi : 0.0f);
                    float dj = lane_bcast((jcur < 64) ? dl2 : dh2, jcur & 63);
                    if (lane == (jcur & 63)) {
                        if (jcur < 64) h_lo += dj; else h_hi += dj;
                    }
                    if (jcur < 64) {
                        rem_lo = (jcur == 63) ? 0ull : (~0ull << (jcur + 1));
                    } else {
                        rem_lo = 0ull;
                        rem_hi = (jcur == 127) ? 0ull : (~0ull << (jcur - 63));
                    }
                    s_lo = fmaf(pcur.x, dj, s_lo);
                    s_hi = fmaf(pcur.y, dj, s_hi);

                    // actual next violator
                    m1b = __ballot((s_lo > a_lo) || (s_lo < -a_lo)) & rem_lo;
                    m2b = __ballot((s_hi > a_hi) || (s_hi < -a_hi)) & rem_hi;
                    int jn = m1b ? (int)__ffsll((unsigned long long)m1b) - 1
                           : (m2b ? 64 + (int)__ffsll((unsigned long long)m2b) - 1 : -1);
                    if (jn >= 0) {
                        if (jn == jspec) pcur = pspec;                    // hit
                        else pcur = vpair[(jn << 6) + (lane ^ ((jn & 3) << 2))];
                    }
                    jcur = jn;
                }
            } else {
                // ---- bisection between pi_bar (s=0) and adj (s), s-space ----
                float hin_lo = tgt_lo, hin_hi = tgt_hi;
                float sin_lo = 0.0f, sin_hi = 0.0f;
                float hout_lo = h_lo, hout_hi = h_hi;
                float sout_lo = s_lo, sout_hi = s_hi;
                float hm_lo = 0.0f, hm_hi = 0.0f;
#pragma unroll
                for (int it = 0; it < 10; ++it) {
                    hm_lo = hin_lo + (hout_lo - hin_lo) * 0.5f;
                    hm_hi = hin_hi + (hout_hi - hin_hi) * 0.5f;
                    float sm_lo = sin_lo + (sout_lo - sin_lo) * 0.5f;
                    float sm_hi = sin_hi + (sout_hi - sin_hi) * 0.5f;
                    bool pl = (sm_lo <= aeps_lo) && (sm_lo >= -aeps_lo);
                    bool ph = (sm_hi <= aeps_hi) && (sm_hi >= -aeps_hi);
                    bool inside = (__ballot(pl && ph) == ~0ull);
                    if (inside) {
                        hin_lo = hm_lo; hin_hi = hm_hi;
                        sin_lo = sm_lo; sin_hi = sm_hi;
                    } else {
                        hout_lo = hm_lo; hout_hi = hm_hi;
                        sout_lo = sm_lo; sout_hi = sm_hi;
                    }
                }
                h_lo = hm_lo;
                h_hi = hm_hi;
            }
        }
        // else: no violators -> judge=1, sweep is a no-op, h unchanged

        out[rlo * T * B + t * B + b] = h_lo;
        out[rhi * T * B + t * B + b] = h_hi;
    }

    out[D * T * B + rlo * B + b] = h_lo;
    out[D * T * B + rhi * B + b] = h_hi;
}

extern "C" void kernel_launch(void* const* d_in, const int* in_sizes, int n_in,
                              void* d_out, int out_size, void* d_ws, size_t ws_size,
                              hipStream_t stream) {
    const float* input   = (const float*)d_in[0];
    const float* target  = (const float*)d_in[1];
    const float* returns = (const float*)d_in[2];
    // d_in[3] = hidden (unused by the reference)
    const float* W = (const float*)d_in[4];
    const float* b = (const float*)d_in[5];
    float* out = (float*)d_out;

    float* vT   = (float*)d_ws;            // 16384 floats
    float* vd   = vT + D * D;              // 128 floats
    float* absb = vd + D;                  // 128 floats

    prep_kernel<<<D, 64, 0, stream>>>(W, b, vT, vd, absb);
    rnn_kernel<<<B / 2, 128, 0, stream>>>(input, target, returns, vT, vd, absb, out);
}

// Round 9
// 225.235 us; speedup vs baseline: 1.6043x; 1.6043x over previous
//
#include <hip/hip_runtime.h>
#include <cstdint>

#define D 128
#define T 64
#define B 512
#define EPSF 1e-5f

// wave-uniform lane broadcast via v_readlane (no LDS/ds_bpermute)
__device__ __forceinline__ float lane_bcast(float x, int l) {
    return __int_as_float(__builtin_amdgcn_readlane(__float_as_int(x), l));
}

// ---------------------------------------------------------------------------
// prep: vT[k*D+i] = v[i][k] = W[i][k]/max(norm_i,1e-12); vd[i]=v[i][i]; absb=|b|
// ---------------------------------------------------------------------------
__global__ __launch_bounds__(64) void prep_kernel(const float* __restrict__ W,
                                                  const float* __restrict__ b,
                                                  float* __restrict__ vT,
                                                  float* __restrict__ vd,
                                                  float* __restrict__ absb) {
    const int i = blockIdx.x;
    const int l = threadIdx.x;
    float w0 = W[i * D + l];
    float w1 = W[i * D + l + 64];
    float p = w0 * w0 + w1 * w1;
#pragma unroll
    for (int off = 32; off; off >>= 1) p += __shfl_xor(p, off);
    float norm = sqrtf(p);
    float scale = norm > 1e-12f ? norm : 1e-12f;
    float v0 = w0 / scale;
    float v1 = w1 / scale;
    vT[l * D + i] = v0;
    vT[(l + 64) * D + i] = v1;
    if (i < 64) {
        if (l == i) vd[i] = v0;
    } else {
        if (l == i - 64) vd[i] = v1;
    }
    if (i == 0) {
        absb[l] = fabsf(b[l]);
        absb[l + 64] = fabsf(b[l + 64]);
    }
}

// ---------------------------------------------------------------------------
// transpose_in: src[r*(T*B) + c] -> dst[c*D + r]   (LDS-tiled, coalesced both
// sides; used for returns [grid (512,2)] and the input t=0 slice [grid (8,2)])
// ---------------------------------------------------------------------------
__global__ __launch_bounds__(256) void transpose_in(const float* __restrict__ src,
                                                    float* __restrict__ dst) {
    __shared__ float tile[64][65];
    const int TBc = T * B;
    const int c0 = blockIdx.x * 64;
    const int r0 = blockIdx.y * 64;
    const int lx = threadIdx.x & 63;
    const int ly = threadIdx.x >> 6;          // 0..3
#pragma unroll
    for (int i = 0; i < 16; ++i) {
        int rr = ly + i * 4;
        tile[rr][lx] = src[(r0 + rr) * TBc + c0 + lx];
    }
    __syncthreads();
#pragma unroll
    for (int i = 0; i < 16; ++i) {
        int cc = ly + i * 4;
        dst[(c0 + cc) * D + r0 + lx] = tile[lx][cc];
    }
}

// ---------------------------------------------------------------------------
// transpose_out: src[c*D + r] -> dst[r*(T*B) + c]; tiles covering the last
// time slice (c >= (T-1)*B) also emit hidden = dst[D*T*B + r*B + b].
// ---------------------------------------------------------------------------
__global__ __launch_bounds__(256) void transpose_out_k(const float* __restrict__ src,
                                                       float* __restrict__ dst) {
    __shared__ float tile[64][65];
    const int TBc = T * B;
    const int c0 = blockIdx.x * 64;
    const int r0 = blockIdx.y * 64;
    const int lx = threadIdx.x & 63;
    const int ly = threadIdx.x >> 6;          // 0..3
#pragma unroll
    for (int i = 0; i < 16; ++i) {
        int cc = ly + i * 4;
        tile[cc][lx] = src[(c0 + cc) * D + r0 + lx];
    }
    __syncthreads();
#pragma unroll
    for (int i = 0; i < 16; ++i) {
        int rr = ly + i * 4;
        dst[(r0 + rr) * TBc + c0 + lx] = tile[lx][rr];
    }
    if (c0 >= (T - 1) * B) {                  // hidden slice (h_last)
        const int boff = c0 - (T - 1) * B;
#pragma unroll
        for (int i = 0; i < 16; ++i) {
            int rr = ly + i * 4;
            dst[D * TBc + (r0 + rr) * B + boff + lx] = tile[lx][rr];
        }
    }
}

// ---------------------------------------------------------------------------
// main RNN kernel = round-4 verbatim (best: 140.3us), templated on addressing.
// COAL=1: inp0[b*D+r] / ret_t[(t*B+b)*D+r] / out_tmp[(t*B+b)*D+r] — every
// per-step global access is 256B unit-stride, full-line stores (no RFO).
// COAL=0: original direct layouts (fallback when ws is too small).
//
// Round-8 insight (counter-closed budget): step time 5360cy == per-CU HBM
// traffic 10.2KB / 1.9 B/cy — the kernel is bound on 4-5.6x AMPLIFIED
// scattered HBM traffic (each lane's 4B store dirties a separate 64B line
// + RFO fetch; returns loads scatter identically). Compute changes bounced
// off this floor for 8 rounds. This round removes the amplification.
//
// One wave per batch column; lane owns rows (lane, lane+64). NO barriers in
// the t-loop (r1: -62%). Matvec from AGPR-pinned registers (r4). Correction
// phase verbatim round-0/round-4.
// ---------------------------------------------------------------------------
template <int COAL>
__global__ __launch_bounds__(128, 1) void rnn_kernel(const float* __restrict__ input,
                                                     const float* __restrict__ target,
                                                     const float* __restrict__ rets,
                                                     const float* __restrict__ vTg,
                                                     const float* __restrict__ vdg,
                                                     const float* __restrict__ absbg,
                                                     float* __restrict__ outp) {
    __shared__ float vsh[D * D];   // exactly 64 KB

    const int tid = threadIdx.x;
    // cooperative swizzled load of vT (plain layout in ws -> swizzled LDS)
    {
        const float4* src = (const float4*)vTg;
        float4* dst = (float4*)vsh;
#pragma unroll
        for (int c = 0; c < 32; ++c) {
            int f = c * 128 + tid;          // source float4 index
            int k = f >> 5;                 // row k of vT
            int i = (f & 31) << 2;          // starting i of this float4
            int ck = (k & 7) << 2;
            int d4 = k * 32 + (((i ^ ck)) >> 2);
            dst[d4] = src[f];
        }
    }
    __syncthreads();

    const int w = tid >> 6;
    const int lane = tid & 63;
    const int b = blockIdx.x * 2 + w;
    const int rlo = lane, rhi = lane + 64;

    const float tgt_lo = target[rlo], tgt_hi = target[rhi];
    const float a_lo = absbg[rlo], a_hi = absbg[rhi];
    const float aeps_lo = a_lo + EPSF, aeps_hi = a_hi + EPSF;
    const float vd_lo = vdg[rlo], vd_hi = vdg[rhi];
    const float rvd_lo = 1.0f / vd_lo, rvd_hi = 1.0f / vd_hi;

    // row-read xor bases: vsh[k*128 + ax[k&7]] (+64 for hi row)
    int ax[8];
#pragma unroll
    for (int c = 0; c < 8; ++c) ax[c] = rlo ^ (c << 2);

    // ---- register-resident v rows, PINNED in AGPRs (one-time LDS read;
    //      "+a" asm result is non-rematerializable -> stays resident) ----
    float vl[D], vh[D];
#pragma unroll
    for (int k = 0; k < D; ++k) {
        int base = k * 128 + ax[k & 7];
        vl[k] = vsh[base];
        vh[k] = vsh[base + 64];
        asm volatile("" : "+a"(vl[k]), "+a"(vh[k]));
    }

    // parallel-judge column bases: candidate j=lane reads float4 at
    // Abase[c] + 32*a  (logical i0 = a*32 + c*4); candidate lane+64 at +8192
    const int cj = (lane & 7) << 2;
    int Abase[8];
#pragma unroll
    for (int c = 0; c < 8; ++c) Abase[c] = lane * 128 + ((c << 2) ^ cj);

    float h_lo, h_hi, r_lo, r_hi;
    if (COAL) {
        h_lo = input[(b << 7) + rlo];             // inp0[b*D + r]
        h_hi = input[(b << 7) + rhi];
        outp[(b << 7) + rlo] = h_lo;              // out_tmp[(0*B+b)*D + r]
        outp[(b << 7) + rhi] = h_hi;
        r_lo = rets[(b << 7) + rlo];              // ret_t[(0*B+b)*D + r]
        r_hi = rets[(b << 7) + rhi];
    } else {
        h_lo = input[rlo * T * B + b];
        h_hi = input[rhi * T * B + b];
        outp[rlo * T * B + b] = h_lo;
        outp[rhi * T * B + b] = h_hi;
        r_lo = rets[rlo * T * B + b];
        r_hi = rets[rhi * T * B + b];
    }

    for (int t = 1; t < T; ++t) {
        // ---- adj = h*(1+r)/(1 + sum(h*r)) ----
        float num_lo = h_lo * (1.0f + r_lo);
        float num_hi = h_hi * (1.0f + r_hi);
        float p = h_lo * r_lo + h_hi * r_hi;
#pragma unroll
        for (int off = 32; off; off >>= 1) p += __shfl_xor(p, off);
        float den = 1.0f + p;
        float adj_lo = num_lo / den;
        float adj_hi = num_hi / den;

        if (t < T - 1) {
            if (COAL) {
                r_lo = rets[((t * B + b) << 7) + rlo];
                r_hi = rets[((t * B + b) << 7) + rhi];
            } else {
                r_lo = rets[rlo * T * B + t * B + b];
                r_hi = rets[rhi * T * B + t * B + b];
            }
        }

        const float x_lo = adj_lo - tgt_lo;
        const float x_hi = adj_hi - tgt_hi;

        // ---- s = v @ (adj - pi_bar): readlane broadcast + AGPR-resident v.
        //      k ascending, single accumulator per row -> bit-identical. ----
        float s_lo = 0.0f, s_hi = 0.0f;
#pragma unroll
        for (int k = 0; k < 64; ++k) {
            float xb = lane_bcast(x_lo, k);
            s_lo = fmaf(vl[k], xb, s_lo);
            s_hi = fmaf(vh[k], xb, s_hi);
        }
#pragma unroll
        for (int k = 0; k < 64; ++k) {
            float xb = lane_bcast(x_hi, k);
            s_lo = fmaf(vl[64 + k], xb, s_lo);
            s_hi = fmaf(vh[64 + k], xb, s_hi);
        }

        h_lo = adj_lo;
        h_hi = adj_hi;

        // ================= correction (verbatim round-0/round-4) ===========
        bool viol_lo = (s_lo > a_lo) || (s_lo < -a_lo);
        bool viol_hi = (s_hi > a_hi) || (s_hi < -a_hi);
        uint64_t mlo = __ballot(viol_lo);
        uint64_t mhi = __ballot(viol_hi);

        if ((mlo | mhi) != 0ull) {
            // per-lane deltas (reference lam formulas, IEEE div)
            float dl = 0.0f, dh = 0.0f;
            if (s_lo > a_lo) dl = (a_lo - s_lo) / vd_lo;
            else if (s_lo < -a_lo) dl = (-a_lo - s_lo) / vd_lo;
            if (s_hi > a_hi) dh = (a_hi - s_hi) / vd_hi;
            else if (s_hi < -a_hi) dh = (-a_hi - s_hi) / vd_hi;

            int V = __popcll(mlo) + __popcll(mhi);
            bool judge;

            if (V <= 8) {
                // q0: all strictly inside a+eps and (V<64 so) a zero-delta
                // column exists
                bool in_lo = (s_lo < aeps_lo) && (s_lo > -aeps_lo);
                bool in_hi = (s_hi < aeps_hi) && (s_hi > -aeps_hi);
                judge = (__ballot(in_lo && in_hi) == ~0ull);
                if (!judge) {
                    uint64_t t_mlo = mlo, t_mhi = mhi;
                    while (t_mlo | t_mhi) {
                        int j;
                        float dj;
                        if (t_mlo) {
                            int jl = (int)__ffsll((unsigned long long)t_mlo) - 1;
                            t_mlo &= t_mlo - 1;
                            j = jl;
                            dj = lane_bcast(dl, jl);
                        } else {
                            int jh = (int)__ffsll((unsigned long long)t_mhi) - 1;
                            t_mhi &= t_mhi - 1;
                            j = 64 + jh;
                            dj = lane_bcast(dh, jh);
                        }
                        int cjj = (j & 7) << 2;
                        int base = j * 128 + (rlo ^ cjj);
                        float n_lo = fmaf(vsh[base], dj, s_lo);
                        float n_hi = fmaf(vsh[base + 64], dj, s_hi);
                        bool pl = (n_lo < aeps_lo) && (n_lo > -aeps_lo);
                        bool ph = (n_hi < aeps_hi) && (n_hi > -aeps_hi);
                        if (__ballot(pl && ph) == ~0ull) { judge = true; break; }
                    }
                }
            } else {
                // ---- parallel judge: lane tests candidates j=lane, lane+64.
                float m1 = -1.0f, m2 = -1.0f;   // only the sign of max matters
#pragma unroll
                for (int a = 0; a < 4; ++a) {
#pragma unroll
                    for (int c = 0; c < 8; ++c) {
                        const int i0 = a * 32 + c * 4;
                        const float* p1 = &vsh[Abase[c] + 32 * a];
                        float4 c1 = *(const float4*)p1;
                        float4 c2 = *(const float4*)(p1 + 8192);
#pragma unroll
                        for (int e = 0; e < 4; ++e) {
                            const int i = i0 + e;
                            float sv = (i < 64) ? lane_bcast(s_lo, i)
                                                : lane_bcast(s_hi, i - 64);
                            float ae = (i < 64) ? lane_bcast(aeps_lo, i)
                                                : lane_bcast(aeps_hi, i - 64);
                            float f1 = ((const float*)&c1)[e];
                            float f2 = ((const float*)&c2)[e];
                            m1 = fmaxf(m1, fabsf(fmaf(f1, dl, sv)) - ae);
                            m2 = fmaxf(m2, fabsf(fmaf(f2, dh, sv)) - ae);
                        }
                    }
                }
                judge = ((__ballot(m1 < 0.0f) | __ballot(m2 < 0.0f)) != 0ull);
            }

            if (judge) {
                // ---- Gauss-Seidel sweep (ascending j, violators only) ----
                uint64_t rem_lo = ~0ull, rem_hi = ~0ull;
                while (true) {
                    uint64_t m1b = __ballot((s_lo > a_lo) || (s_lo < -a_lo)) & rem_lo;
                    uint64_t m2b = __ballot((s_hi > a_hi) || (s_hi < -a_hi)) & rem_hi;
                    int j;
                    if (m1b) {
                        int jl = (int)__ffsll((unsigned long long)m1b) - 1;
                        j = jl;
                        rem_lo = (jl == 63) ? 0ull : (~0ull << (jl + 1));
                    } else if (m2b) {
                        int jh = (int)__ffsll((unsigned long long)m2b) - 1;
                        j = 64 + jh;
                        rem_lo = 0ull;
                        rem_hi = (jh == 63) ? 0ull : (~0ull << (jh + 1));
                    } else {
                        break;
                    }
                    float dl2 = (s_lo > a_lo) ? (a_lo - s_lo) * rvd_lo
                               : ((s_lo < -a_lo) ? (-a_lo - s_lo) * rvd_lo : 0.0f);
                    float dh2 = (s_hi > a_hi) ? (a_hi - s_hi) * rvd_hi
                               : ((s_hi < -a_hi) ? (-a_hi - s_hi) * rvd_hi : 0.0f);
                    float srcv = (j < 64) ? dl2 : dh2;
                    float dj = lane_bcast(srcv, j & 63);
                    if (lane == (j & 63)) {
                        if (j < 64) h_lo += dj; else h_hi += dj;
                    }
                    int cjj = (j & 7) << 2;
                    int base = j * 128 + (rlo ^ cjj);
                    s_lo = fmaf(vsh[base], dj, s_lo);
                    s_hi = fmaf(vsh[base + 64], dj, s_hi);
                }
            } else {
                // ---- bisection between pi_bar (s=0) and adj (s), s-space ----
                float hin_lo = tgt_lo, hin_hi = tgt_hi;
                float sin_lo = 0.0f, sin_hi = 0.0f;
                float hout_lo = h_lo, hout_hi = h_hi;
                float sout_lo = s_lo, sout_hi = s_hi;
                float hm_lo = 0.0f, hm_hi = 0.0f;
#pragma unroll
                for (int it = 0; it < 10; ++it) {
                    hm_lo = hin_lo + (hout_lo - hin_lo) * 0.5f;
                    hm_hi = hin_hi + (hout_hi - hin_hi) * 0.5f;
                    float sm_lo = sin_lo + (sout_lo - sin_lo) * 0.5f;
                    float sm_hi = sin_hi + (sout_hi - sin_hi) * 0.5f;
                    bool pl = (sm_lo <= aeps_lo) && (sm_lo >= -aeps_lo);
                    bool ph = (sm_hi <= aeps_hi) && (sm_hi >= -aeps_hi);
                    bool inside = (__ballot(pl && ph) == ~0ull);
                    if (inside) {
                        hin_lo = hm_lo; hin_hi = hm_hi;
                        sin_lo = sm_lo; sin_hi = sm_hi;
                    } else {
                        hout_lo = hm_lo; hout_hi = hm_hi;
                        sout_lo = sm_lo; sout_hi = sm_hi;
                    }
                }
                h_lo = hm_lo;
                h_hi = hm_hi;
            }
        }
        // else: no violators -> judge=1, sweep is a no-op, h unchanged

        if (COAL) {
            outp[((t * B + b) << 7) + rlo] = h_lo;
            outp[((t * B + b) << 7) + rhi] = h_hi;
        } else {
            outp[rlo * T * B + t * B + b] = h_lo;
            outp[rhi * T * B + t * B + b] = h_hi;
        }
    }

    if (!COAL) {       // COAL path: hidden emitted by transpose_out_k
        outp[D * T * B + rlo * B + b] = h_lo;
        outp[D * T * B + rhi * B + b] = h_hi;
    }
}

extern "C" void kernel_launch(void* const* d_in, const int* in_sizes, int n_in,
                              void* d_out, int out_size, void* d_ws, size_t ws_size,
                              hipStream_t stream) {
    const float* input   = (const float*)d_in[0];
    const float* target  = (const float*)d_in[1];
    const float* returns = (const float*)d_in[2];
    // d_in[3] = hidden (unused by the reference)
    const float* W = (const float*)d_in[4];
    const float* b = (const float*)d_in[5];
    float* out = (float*)d_out;

    float* vT   = (float*)d_ws;                    // 16384 floats
    float* vd   = vT + D * D;                      // 128
    float* absb = vd + D;                          // 128
    float* inp0 = absb + D;                        // D*B      = 65536
    float* rett = inp0 + D * B;                    // T*B*D    = 4194304
    float* outt = rett + (size_t)T * B * D;        // T*B*D    = 4194304

    const size_t need = ((size_t)(D * D + 2 * D + D * B) + 2ull * T * B * D)
                        * sizeof(float);

    prep_kernel<<<D, 64, 0, stream>>>(W, b, vT, vd, absb);

    if (ws_size >= need) {
        // coalesced path: pre-transpose returns + input slice, RNN on linear
        // [c][r] records, post-transpose outputs (+hidden).
        transpose_in<<<dim3(T * B / 64, 2), 256, 0, stream>>>(returns, rett);
        transpose_in<<<dim3(B / 64, 2), 256, 0, stream>>>(input, inp0);
        rnn_kernel<1><<<B / 2, 128, 0, stream>>>(inp0, target, rett, vT, vd,
                                                 absb, outt);
        transpose_out_k<<<dim3(T * B / 64, 2), 256, 0, stream>>>(outt, out);
    } else {
        // fallback: round-4 verbatim (direct layouts)
        rnn_kernel<0><<<B / 2, 128, 0, stream>>>(input, target, returns, vT,
                                                 vd, absb, out);
    }
}